// Round 8
// baseline (870.574 us; speedup 1.0000x reference)
//
#include <hip/hip_runtime.h>
#include <hip/hip_fp16.h>

#define L_ 13
#define B_ 32
#define S_ 128
#define H_ 768
#define NU 32
#define GG 64
#define TU 96
#define LN_EPS 1e-3f
#define SEQ_ST 68      // seq LDS row stride (floats)
#define XT_ST 129      // xT2 row stride (half2 units) — odd => conflict-free
#define WK_ST 100      // wk2 row stride (half2 units per k2-row)

// DPP controls
#define DPP_X1  0xB1
#define DPP_X2  0x4E
#define DPP_X7  0x141
#define DPP_X15 0x140

typedef float v2f __attribute__((ext_vector_type(2)));
typedef _Float16 h2t __attribute__((ext_vector_type(2)));
typedef unsigned int uv2 __attribute__((ext_vector_type(2)));

union F4H8 { float4 f4; __half2 hh[4]; h2t h[4]; };
union FH2  { float f; __half2 hh; h2t h; };
union F2H2 { float2 f2; __half2 hh[2]; };
union U2H4 { uint2 u; __half2 hh[2]; };

__device__ __forceinline__ float sigmoidf_(float a) { return 1.0f / (1.0f + __expf(-a)); }
__device__ __forceinline__ float tanhf_(float a) { float e = __expf(-2.0f * a); return (1.0f - e) / (1.0f + e); }
__device__ __forceinline__ void pkfma(v2f& a, v2f x, v2f w) {
    asm("v_pk_fma_f32 %0, %1, %2, %0" : "+v"(a) : "v"(x), "v"(w));
}
template <int CTRL>
__device__ __forceinline__ float dppf(float x) {
    return __int_as_float(__builtin_amdgcn_update_dpp(
        0, __float_as_int(x), CTRL, 0xF, 0xF, true));
}

// ---------------- lin_all = xs @ W_lin + b_lin for ALL 13 layers (fp16 out) ----------------
__global__ __launch_bounds__(256) void lin_kernel(
    const float* __restrict__ xs, const float* __restrict__ Wl,
    const float* __restrict__ bl, __half* __restrict__ lin)
{
    __shared__ float sA[64][68];
    __shared__ float sW[64][68];
    const int t = threadIdx.x;
    const size_t row0 = (size_t)blockIdx.x * 64;
    const int r4 = (t >> 4) << 2;
    const int c4 = (t & 15) << 2;

    float acc[4][4];
    #pragma unroll
    for (int i = 0; i < 4; ++i)
        #pragma unroll
        for (int j = 0; j < 4; ++j) acc[i][j] = 0.f;

    for (int kt = 0; kt < H_; kt += 64) {
        #pragma unroll
        for (int p = 0; p < 4; ++p) {
            int idx = t + 256 * p;
            int r = idx >> 4, cc = (idx & 15) << 2;
            *(float4*)&sA[r][cc] = *(const float4*)&xs[(row0 + r) * H_ + kt + cc];
            *(float4*)&sW[r][cc] = *(const float4*)&Wl[(size_t)(kt + r) * GG + cc];
        }
        __syncthreads();
        #pragma unroll 8
        for (int k = 0; k < 64; ++k) {
            float a0 = sA[r4 + 0][k], a1 = sA[r4 + 1][k], a2 = sA[r4 + 2][k], a3 = sA[r4 + 3][k];
            float4 w = *(const float4*)&sW[k][c4];
            acc[0][0] += a0 * w.x; acc[0][1] += a0 * w.y; acc[0][2] += a0 * w.z; acc[0][3] += a0 * w.w;
            acc[1][0] += a1 * w.x; acc[1][1] += a1 * w.y; acc[1][2] += a1 * w.z; acc[1][3] += a1 * w.w;
            acc[2][0] += a2 * w.x; acc[2][1] += a2 * w.y; acc[2][2] += a2 * w.z; acc[2][3] += a2 * w.w;
            acc[3][0] += a3 * w.x; acc[3][1] += a3 * w.y; acc[3][2] += a3 * w.z; acc[3][3] += a3 * w.w;
        }
        __syncthreads();
    }
    float4 bv = *(const float4*)&bl[c4];
    #pragma unroll
    for (int i = 0; i < 4; ++i) {
        F2H2 u;
        u.hh[0] = __floats2half2_rn(acc[i][0] + bv.x, acc[i][1] + bv.y);
        u.hh[1] = __floats2half2_rn(acc[i][2] + bv.z, acc[i][3] + bv.w);
        *(float2*)&lin[(row0 + r4 + i) * GG + c4] = u.f2;
    }
}

// ---------------- one block per batch: 13 x (LN + xp + bidir GRU scan) + classifier ----------------
__global__ __launch_bounds__(512) void chain_kernel(
    const __half* __restrict__ lin_all,
    const float* __restrict__ Wr_f, const float* __restrict__ b_f,
    const float* __restrict__ Wr_b, const float* __restrict__ b_b,
    const float* __restrict__ Wk_f, const float* __restrict__ Wk_b,
    const float* __restrict__ ln_g, const float* __restrict__ ln_b,
    const float* __restrict__ W_cls, const float* __restrict__ b_cls,
    float* __restrict__ out)
{
    extern __shared__ float sm[];
    float*   seqb = sm;                                        // [128][SEQ_ST] f32
    __half2* xt2  = (__half2*)(sm + 8704);                     // [32][XT_ST]  x, k-pairs
    __half2* wk2  = (__half2*)(sm + 8704 + 4128);              // [2][32][WK_ST]
    __half*  xps  = (__half*)(sm + 8704 + 4128 + 6400);        // [2][128][32][4] fp16
    float*   hbf  = sm + 8704 + 4128 + 6400 + 16384;           // [32]
    float*   hbb  = hbf + NU;

    const int b = blockIdx.x;
    const int t = threadIdx.x;
    const int wave = t >> 6;
    const int lane = t & 63;
    const int v16 = lane & 15;
    const int u = v16 + 16 * ((lane >> 5) & 1);

    for (int i = t; i < S_ * SEQ_ST; i += 512) seqb[i] = 0.f;
    // stage Wk (layer-invariant) into LDS as half2 k-pairs
    for (int i = t; i < 2 * 32 * 96; i += 512) {
        const int d = i / 3072, rem = i - d * 3072, k2 = rem / 96, c = rem - k2 * 96;
        const float* W = d ? Wk_b : Wk_f;
        wk2[(d * 32 + k2) * WK_ST + c] =
            __floats2half2_rn(W[(2 * k2) * TU + c], W[(2 * k2 + 1) * TU + c]);
    }

    // ---- scan-wave persistent state (waves 0=fwd, 1=bwd) ----
    // lo butterfly (units 0-15) / hi butterfly (units 16-31), uniform for all lanes
    v2f wz_lo[8], wr_lo[8], wh_lo[8], wz_hi[8], wr_hi[8], wh_hi[8];
    float hn = 0.f, rbz = 0.f, rbr = 0.f, rbh = 0.f;
    if (wave < 2) {
        const float* Wr   = wave ? Wr_b : Wr_f;
        const float* bias = wave ? b_b  : b_f;
        const int ex[8] = {0, 2, 7, 5, 15, 13, 8, 10};
        const int ey[8] = {1, 3, 6, 4, 14, 12, 9, 11};
        #pragma unroll
        for (int m = 0; m < 8; ++m) {
            const int jx = v16 ^ ex[m], jy = v16 ^ ey[m];
            wz_lo[m] = v2f{ Wr[jx * TU + u],          Wr[jy * TU + u] };
            wr_lo[m] = v2f{ Wr[jx * TU + NU + u],     Wr[jy * TU + NU + u] };
            wh_lo[m] = v2f{ Wr[jx * TU + 2 * NU + u], Wr[jy * TU + 2 * NU + u] };
            wz_hi[m] = v2f{ Wr[(16 + jx) * TU + u],          Wr[(16 + jy) * TU + u] };
            wr_hi[m] = v2f{ Wr[(16 + jx) * TU + NU + u],     Wr[(16 + jy) * TU + NU + u] };
            wh_hi[m] = v2f{ Wr[(16 + jx) * TU + 2 * NU + u], Wr[(16 + jy) * TU + 2 * NU + u] };
        }
        rbz = bias[TU + u]; rbr = bias[TU + NU + u]; rbh = bias[TU + 2 * NU + u];
    }

    // phase-1 mapping: 8-lane LN groups, 8 cols each, 2 passes
    const int g8 = t >> 3;
    const int c8 = (t & 7) << 3;
    // phase-2 mapping
    const int rgrp = t & 31;
    const int cg = t >> 5;
    const int dsel = cg >> 3;
    const int cc = (cg & 7) * 12;
    const float* bias0 = dsel ? b_b : b_f;
    const __half2* wkd = wk2 + dsel * 32 * WK_ST;
    __half* xpd = xps + dsel * (S_ * 128);

    __syncthreads();

    for (int l = 0; l < L_; ++l) {
        const __half* linb = lin_all + (size_t)(l * B_ + b) * S_ * GG;

        // ---- phase 1: x = LN(lin + seq) -> fp16 k-pair transposed into xt2 ----
        #pragma unroll
        for (int p = 0; p < 2; ++p) {
            const int r = g8 + 64 * p;
            F4H8 lu; lu.f4 = *(const float4*)&linb[(size_t)r * GG + c8];
            float4 s0 = *(const float4*)&seqb[r * SEQ_ST + c8];
            float4 s1 = *(const float4*)&seqb[r * SEQ_ST + c8 + 4];
            float2 l0 = __half22float2(lu.hh[0]);
            float2 l1 = __half22float2(lu.hh[1]);
            float2 l2 = __half22float2(lu.hh[2]);
            float2 l3 = __half22float2(lu.hh[3]);
            float v[8];
            v[0] = l0.x + s0.x; v[1] = l0.y + s0.y; v[2] = l1.x + s0.z; v[3] = l1.y + s0.w;
            v[4] = l2.x + s1.x; v[5] = l2.y + s1.y; v[6] = l3.x + s1.z; v[7] = l3.y + s1.w;
            float s = 0.f;
            #pragma unroll
            for (int j = 0; j < 8; ++j) s += v[j];
            #pragma unroll
            for (int off = 1; off < 8; off <<= 1) s += __shfl_xor(s, off);
            const float mean = s * 0.015625f;
            float q = 0.f;
            float d[8];
            #pragma unroll
            for (int j = 0; j < 8; ++j) { d[j] = v[j] - mean; q += d[j] * d[j]; }
            #pragma unroll
            for (int off = 1; off < 8; off <<= 1) q += __shfl_xor(q, off);
            const float rstd = rsqrtf(q * 0.015625f + LN_EPS);
            float4 g0 = *(const float4*)&ln_g[c8];
            float4 g1 = *(const float4*)&ln_g[c8 + 4];
            float4 b0 = *(const float4*)&ln_b[c8];
            float4 b1 = *(const float4*)&ln_b[c8 + 4];
            float x[8];
            x[0] = d[0] * rstd * g0.x + b0.x; x[1] = d[1] * rstd * g0.y + b0.y;
            x[2] = d[2] * rstd * g0.z + b0.z; x[3] = d[3] * rstd * g0.w + b0.w;
            x[4] = d[4] * rstd * g1.x + b1.x; x[5] = d[5] * rstd * g1.y + b1.y;
            x[6] = d[6] * rstd * g1.z + b1.z; x[7] = d[7] * rstd * g1.w + b1.w;
            #pragma unroll
            for (int j = 0; j < 4; ++j)
                xt2[(c8 / 2 + j) * XT_ST + r] = __floats2half2_rn(x[2 * j], x[2 * j + 1]);
        }
        __syncthreads();

        // ---- phase 2: xp = x @ Wk + bias0 via v_dot2_f32_f16; write [row][unit][slot] fp16 ----
        {
            float acc[4][12];
            #pragma unroll
            for (int m = 0; m < 12; ++m) {
                const float bi = bias0[cc + m];
                acc[0][m] = bi; acc[1][m] = bi; acc[2][m] = bi; acc[3][m] = bi;
            }
            #pragma unroll 4
            for (int k2 = 0; k2 < 32; ++k2) {
                FH2 x0, x1, x2, x3;
                x0.hh = xt2[k2 * XT_ST + rgrp];
                x1.hh = xt2[k2 * XT_ST + rgrp + 32];
                x2.hh = xt2[k2 * XT_ST + rgrp + 64];
                x3.hh = xt2[k2 * XT_ST + rgrp + 96];
                F4H8 wa, wb, wc;
                wa.f4 = *(const float4*)&wkd[k2 * WK_ST + cc];
                wb.f4 = *(const float4*)&wkd[k2 * WK_ST + cc + 4];
                wc.f4 = *(const float4*)&wkd[k2 * WK_ST + cc + 8];
                #pragma unroll
                for (int m = 0; m < 4; ++m) {
                    acc[0][m]     = __builtin_amdgcn_fdot2(x0.h, wa.h[m], acc[0][m],     false);
                    acc[1][m]     = __builtin_amdgcn_fdot2(x1.h, wa.h[m], acc[1][m],     false);
                    acc[2][m]     = __builtin_amdgcn_fdot2(x2.h, wa.h[m], acc[2][m],     false);
                    acc[3][m]     = __builtin_amdgcn_fdot2(x3.h, wa.h[m], acc[3][m],     false);
                    acc[0][m + 4] = __builtin_amdgcn_fdot2(x0.h, wb.h[m], acc[0][m + 4], false);
                    acc[1][m + 4] = __builtin_amdgcn_fdot2(x1.h, wb.h[m], acc[1][m + 4], false);
                    acc[2][m + 4] = __builtin_amdgcn_fdot2(x2.h, wb.h[m], acc[2][m + 4], false);
                    acc[3][m + 4] = __builtin_amdgcn_fdot2(x3.h, wb.h[m], acc[3][m + 4], false);
                    acc[0][m + 8] = __builtin_amdgcn_fdot2(x0.h, wc.h[m], acc[0][m + 8], false);
                    acc[1][m + 8] = __builtin_amdgcn_fdot2(x1.h, wc.h[m], acc[1][m + 8], false);
                    acc[2][m + 8] = __builtin_amdgcn_fdot2(x2.h, wc.h[m], acc[2][m + 8], false);
                    acc[3][m + 8] = __builtin_amdgcn_fdot2(x3.h, wc.h[m], acc[3][m + 8], false);
                }
            }
            #pragma unroll
            for (int i = 0; i < 4; ++i) {
                const int r = rgrp + 32 * i;
                #pragma unroll
                for (int m = 0; m < 12; ++m) {
                    const int c = cc + m;
                    xpd[r * 128 + (c & 31) * 4 + (c >> 5)] = __float2half(acc[i][m]);
                }
            }
        }
        __syncthreads();

        // ---- phase 3: scans; permlane32_swap h-exchange (VALU), 1 ds_read_b64/step, 2-deep prefetch ----
        if (wave < 2) {
            const int dir = wave;
            const __half* xp = xps + dir * (S_ * 128);
            float* sq = seqb + dir * NU + u;
            const int stp = dir ? -1 : 1;
            int s = dir ? (S_ - 1) : 0;
            const bool wr_lane = ((lane & 16) == 0);
            U2H4 cur, nxt;
            cur.u = *(const uint2*)&xp[s * 128 + 4 * u];
            nxt.u = *(const uint2*)&xp[(s + stp) * 128 + 4 * u];
            #pragma unroll 2
            for (int st = 0; st < S_; ++st) {
                int spf = s + 2 * stp;
                spf = spf < 0 ? 0 : (spf > S_ - 1 ? S_ - 1 : spf);
                U2H4 pf; pf.u = *(const uint2*)&xp[spf * 128 + 4 * u];

                // VALU-only h-broadcast: both halves to every lane
                uv2 sw = __builtin_amdgcn_permlane32_swap(
                    __float_as_uint(hn), __float_as_uint(hn), false, false);
                const float lo = __uint_as_float(sw.x);   // h[v16]      (units 0-15)
                const float hi = __uint_as_float(sw.y);   // h[16+v16]   (units 16-31)

                v2f ro[8], rt[8];
                ro[0].x = lo;                 ro[0].y = dppf<DPP_X1>(lo);
                ro[1].x = dppf<DPP_X2>(ro[0].x);  ro[1].y = dppf<DPP_X2>(ro[0].y);
                ro[2].x = dppf<DPP_X7>(ro[0].x);  ro[2].y = dppf<DPP_X7>(ro[0].y);
                ro[3].x = dppf<DPP_X7>(ro[1].x);  ro[3].y = dppf<DPP_X7>(ro[1].y);
                ro[4].x = dppf<DPP_X15>(ro[0].x); ro[4].y = dppf<DPP_X15>(ro[0].y);
                ro[5].x = dppf<DPP_X15>(ro[1].x); ro[5].y = dppf<DPP_X15>(ro[1].y);
                ro[6].x = dppf<DPP_X15>(ro[2].x); ro[6].y = dppf<DPP_X15>(ro[2].y);
                ro[7].x = dppf<DPP_X15>(ro[3].x); ro[7].y = dppf<DPP_X15>(ro[3].y);
                rt[0].x = hi;                 rt[0].y = dppf<DPP_X1>(hi);
                rt[1].x = dppf<DPP_X2>(rt[0].x);  rt[1].y = dppf<DPP_X2>(rt[0].y);
                rt[2].x = dppf<DPP_X7>(rt[0].x);  rt[2].y = dppf<DPP_X7>(rt[0].y);
                rt[3].x = dppf<DPP_X7>(rt[1].x);  rt[3].y = dppf<DPP_X7>(rt[1].y);
                rt[4].x = dppf<DPP_X15>(rt[0].x); rt[4].y = dppf<DPP_X15>(rt[0].y);
                rt[5].x = dppf<DPP_X15>(rt[1].x); rt[5].y = dppf<DPP_X15>(rt[1].y);
                rt[6].x = dppf<DPP_X15>(rt[2].x); rt[6].y = dppf<DPP_X15>(rt[2].y);
                rt[7].x = dppf<DPP_X15>(rt[3].x); rt[7].y = dppf<DPP_X15>(rt[3].y);

                const float xz = __low2float(cur.hh[0]);
                const float xr = __high2float(cur.hh[0]);
                const float xh = __low2float(cur.hh[1]);

                v2f azo = v2f{xz + rbz, 0.f}, azt = v2f{0.f, 0.f};
                v2f aro = v2f{xr + rbr, 0.f}, art = v2f{0.f, 0.f};
                v2f aho = v2f{rbh, 0.f},      aht = v2f{0.f, 0.f};
                #pragma unroll
                for (int m = 0; m < 8; ++m) {
                    pkfma(azo, ro[m], wz_lo[m]); pkfma(azt, rt[m], wz_hi[m]);
                    pkfma(aro, ro[m], wr_lo[m]); pkfma(art, rt[m], wr_hi[m]);
                    pkfma(aho, ro[m], wh_lo[m]); pkfma(aht, rt[m], wh_hi[m]);
                }
                const float zz = (azo.x + azo.y) + (azt.x + azt.y);
                const float rr = (aro.x + aro.y) + (art.x + art.y);
                const float rh = (aho.x + aho.y) + (aht.x + aht.y);
                const float z  = sigmoidf_(zz);
                const float r  = sigmoidf_(rr);
                const float hh = tanhf_(xh + r * rh);
                hn = hh + z * (hn - hh);
                if (wr_lane) sq[s * SEQ_ST] = hn;
                cur = nxt; nxt = pf;
                s += stp;
            }
        }
        __syncthreads();
    }

    // ---- final h + classifier ----
    if (wave < 2 && ((lane & 16) == 0)) (wave ? hbb : hbf)[u] = hn;
    __syncthreads();
    if (t == 0) {
        float l0 = b_cls[0], l1 = b_cls[1];
        for (int j = 0; j < NU; ++j) {
            const float hf = hbf[j], hk = hbb[j];
            l0 += hf * W_cls[4 * j]     + hk * W_cls[4 * j + 2];
            l1 += hf * W_cls[4 * j + 1] + hk * W_cls[4 * j + 3];
        }
        const float m = fmaxf(l0, l1);
        const float e0 = __expf(l0 - m), e1 = __expf(l1 - m);
        const float inv = 1.0f / (e0 + e1);
        out[b * 2 + 0] = e0 * inv;
        out[b * 2 + 1] = e1 * inv;
    }
}

extern "C" void kernel_launch(void* const* d_in, const int* in_sizes, int n_in,
                              void* d_out, int out_size, void* d_ws, size_t ws_size,
                              hipStream_t stream) {
    const float* xs    = (const float*)d_in[0];
    const float* W_lin = (const float*)d_in[1];
    const float* b_lin = (const float*)d_in[2];
    const float* ln_g  = (const float*)d_in[3];
    const float* ln_b  = (const float*)d_in[4];
    const float* Wk_f  = (const float*)d_in[5];
    const float* Wr_f  = (const float*)d_in[6];
    const float* b_f   = (const float*)d_in[7];
    const float* Wk_b  = (const float*)d_in[8];
    const float* Wr_b  = (const float*)d_in[9];
    const float* b_b   = (const float*)d_in[10];
    const float* W_cls = (const float*)d_in[11];
    const float* b_cls = (const float*)d_in[12];
    float* out = (float*)d_out;

    __half* lin_all = (__half*)d_ws;   // 13*4096*64 fp16 = 6,815,744 B

    // floats: seqb 8704 + xt2 4128 + wk2 6400 + xps 16384 + hb 64 = 35,680 -> 142,720 B
    const int smem = (8704 + 4128 + 6400 + 16384 + 64) * (int)sizeof(float);
    (void)hipFuncSetAttribute((const void*)chain_kernel,
                              hipFuncAttributeMaxDynamicSharedMemorySize, smem);

    lin_kernel<<<(L_ * B_ * S_) / 64, 256, 0, stream>>>(xs, W_lin, b_lin, lin_all);

    chain_kernel<<<B_, 512, smem, stream>>>(
        lin_all, Wr_f, b_f, Wr_b, b_b, Wk_f, Wk_b, ln_g, ln_b, W_cls, b_cls, out);
}

// Round 9
// 639.819 us; speedup vs baseline: 1.3607x; 1.3607x over previous
//
#include <hip/hip_runtime.h>
#include <hip/hip_fp16.h>

#define L_ 13
#define B_ 32
#define S_ 128
#define H_ 768
#define NU 32
#define GG 64
#define TU 96
#define LN_EPS 1e-3f
#define SEQ_ST 68      // seq LDS row stride (floats)
#define XT_ST 129      // xT2 row stride (half2 units) — odd => conflict-free
#define WK_ST 100      // wk2 row stride (half2 units per k2-row)
#define XPH_ST 100     // xp row stride (halves)

// DPP controls
#define DPP_X1  0xB1
#define DPP_X2  0x4E
#define DPP_X7  0x141
#define DPP_X15 0x140

typedef float v2f __attribute__((ext_vector_type(2)));
typedef _Float16 h2t __attribute__((ext_vector_type(2)));
typedef unsigned int uv2 __attribute__((ext_vector_type(2)));

union F4H8 { float4 f4; __half2 hh[4]; h2t h[4]; };
union FH2  { float f; __half2 hh; h2t h; };
union F2H2 { float2 f2; __half2 hh[2]; };

__device__ __forceinline__ float sigmoidf_(float a) { return 1.0f / (1.0f + __expf(-a)); }
__device__ __forceinline__ float tanhf_(float a) { float e = __expf(-2.0f * a); return (1.0f - e) / (1.0f + e); }
__device__ __forceinline__ void pkfma(v2f& a, v2f x, v2f w) {
    asm("v_pk_fma_f32 %0, %1, %2, %0" : "+v"(a) : "v"(x), "v"(w));
}
template <int CTRL>
__device__ __forceinline__ float dppf(float x) {
    return __int_as_float(__builtin_amdgcn_update_dpp(
        0, __float_as_int(x), CTRL, 0xF, 0xF, true));
}
// x[l] + x[l^16]: orientation-invariant (.x+.y covers both copies regardless of
// which output is the even/odd-row copy).
__device__ __forceinline__ float pairsum16(float x) {
#if __has_builtin(__builtin_amdgcn_permlane16_swap)
    uv2 s = __builtin_amdgcn_permlane16_swap(
        __float_as_uint(x), __float_as_uint(x), false, false);
    return __uint_as_float(s.x) + __uint_as_float(s.y);
#else
    return x + __shfl_xor(x, 16);
#endif
}

// ---------------- lin_all = xs @ W_lin + b_lin for ALL 13 layers (fp16 out) ----------------
__global__ __launch_bounds__(256) void lin_kernel(
    const float* __restrict__ xs, const float* __restrict__ Wl,
    const float* __restrict__ bl, __half* __restrict__ lin)
{
    __shared__ float sA[64][68];
    __shared__ float sW[64][68];
    const int t = threadIdx.x;
    const size_t row0 = (size_t)blockIdx.x * 64;
    const int r4 = (t >> 4) << 2;
    const int c4 = (t & 15) << 2;

    float acc[4][4];
    #pragma unroll
    for (int i = 0; i < 4; ++i)
        #pragma unroll
        for (int j = 0; j < 4; ++j) acc[i][j] = 0.f;

    for (int kt = 0; kt < H_; kt += 64) {
        #pragma unroll
        for (int p = 0; p < 4; ++p) {
            int idx = t + 256 * p;
            int r = idx >> 4, cc = (idx & 15) << 2;
            *(float4*)&sA[r][cc] = *(const float4*)&xs[(row0 + r) * H_ + kt + cc];
            *(float4*)&sW[r][cc] = *(const float4*)&Wl[(size_t)(kt + r) * GG + cc];
        }
        __syncthreads();
        #pragma unroll 8
        for (int k = 0; k < 64; ++k) {
            float a0 = sA[r4 + 0][k], a1 = sA[r4 + 1][k], a2 = sA[r4 + 2][k], a3 = sA[r4 + 3][k];
            float4 w = *(const float4*)&sW[k][c4];
            acc[0][0] += a0 * w.x; acc[0][1] += a0 * w.y; acc[0][2] += a0 * w.z; acc[0][3] += a0 * w.w;
            acc[1][0] += a1 * w.x; acc[1][1] += a1 * w.y; acc[1][2] += a1 * w.z; acc[1][3] += a1 * w.w;
            acc[2][0] += a2 * w.x; acc[2][1] += a2 * w.y; acc[2][2] += a2 * w.z; acc[2][3] += a2 * w.w;
            acc[3][0] += a3 * w.x; acc[3][1] += a3 * w.y; acc[3][2] += a3 * w.z; acc[3][3] += a3 * w.w;
        }
        __syncthreads();
    }
    float4 bv = *(const float4*)&bl[c4];
    #pragma unroll
    for (int i = 0; i < 4; ++i) {
        F2H2 u;
        u.hh[0] = __floats2half2_rn(acc[i][0] + bv.x, acc[i][1] + bv.y);
        u.hh[1] = __floats2half2_rn(acc[i][2] + bv.z, acc[i][3] + bv.w);
        *(float2*)&lin[(row0 + r4 + i) * GG + c4] = u.f2;
    }
}

// ---------------- one block per batch: 13 x (LN + xp + bidir GRU scan) + classifier ----------------
__global__ __launch_bounds__(512) void chain_kernel(
    const __half* __restrict__ lin_all,
    const float* __restrict__ Wr_f, const float* __restrict__ b_f,
    const float* __restrict__ Wr_b, const float* __restrict__ b_b,
    const float* __restrict__ Wk_f, const float* __restrict__ Wk_b,
    const float* __restrict__ ln_g, const float* __restrict__ ln_b,
    const float* __restrict__ W_cls, const float* __restrict__ b_cls,
    float* __restrict__ out)
{
    extern __shared__ float sm[];
    float*   seqb = sm;                                   // [128][SEQ_ST] f32
    __half2* xt2  = (__half2*)(sm + 8704);                // [32][XT_ST]  x, k-pairs
    __half2* wk2  = (__half2*)(sm + 8704 + 4128);         // [2][32][WK_ST]
    __half*  xph  = (__half*)(sm + 8704 + 4128 + 6400);   // [2][128][XPH_ST]
    float*   hbf  = sm + 8704 + 4128 + 6400 + 12800;      // [32]
    float*   hbb  = hbf + NU;

    const int b = blockIdx.x;
    const int t = threadIdx.x;
    const int wave = t >> 6;
    const int lane = t & 63;
    const int v16 = lane & 15;
    const int b4 = (lane >> 4) & 1;
    const int b5 = (lane >> 5) & 1;
    const int ud = v16 + 16 * b5;      // unit this lane's dot computes
    // storage: h_store[l] = h[(l&15) + 16*b4] — row-local contiguous halves

    for (int i = t; i < S_ * SEQ_ST; i += 512) seqb[i] = 0.f;
    // stage Wk (layer-invariant) into LDS as half2 k-pairs
    for (int i = t; i < 2 * 32 * 96; i += 512) {
        const int d = i / 3072, rem = i - d * 3072, k2 = rem / 96, c = rem - k2 * 96;
        const float* W = d ? Wk_b : Wk_f;
        wk2[(d * 32 + k2) * WK_ST + c] =
            __floats2half2_rn(W[(2 * k2) * TU + c], W[(2 * k2 + 1) * TU + c]);
    }

    // ---- scan-wave persistent state (waves 0=fwd, 1=bwd): row-half weight columns ----
    v2f wz[8], wr_[8], wh[8];
    float h_store = 0.f, h_dot = 0.f, rbz2 = 0.f, rbr2 = 0.f, rbh2 = 0.f;
    if (wave < 2) {
        const float* Wr   = wave ? Wr_b : Wr_f;
        const float* bias = wave ? b_b  : b_f;
        const int ex[8] = {0, 2, 7, 5, 15, 13, 8, 10};
        const int ey[8] = {1, 3, 6, 4, 14, 12, 9, 11};
        const int BB = 16 * b4;        // h-range this lane dots over (own row's)
        #pragma unroll
        for (int m = 0; m < 8; ++m) {
            const int jx = BB + (v16 ^ ex[m]), jy = BB + (v16 ^ ey[m]);
            wz[m]  = v2f{ Wr[jx * TU + ud],          Wr[jy * TU + ud] };
            wr_[m] = v2f{ Wr[jx * TU + NU + ud],     Wr[jy * TU + NU + ud] };
            wh[m]  = v2f{ Wr[jx * TU + 2 * NU + ud], Wr[jy * TU + 2 * NU + ud] };
        }
        // halve: bias/x-init is added by BOTH l^16 partners, then pair-summed
        rbz2 = 0.5f * bias[TU + ud];
        rbr2 = 0.5f * bias[TU + NU + ud];
        rbh2 = 0.5f * bias[TU + 2 * NU + ud];
    }

    // phase-1 mapping: 8-lane LN groups, 8 cols each, 2 passes
    const int g8 = t >> 3;
    const int c8 = (t & 7) << 3;
    // phase-2 mapping
    const int rgrp = t & 31;
    const int cg = t >> 5;
    const int dsel = cg >> 3;
    const int cc = (cg & 7) * 12;
    const float* bias0 = dsel ? b_b : b_f;
    const __half2* wkd = wk2 + dsel * 32 * WK_ST;
    __half* xpd = xph + dsel * (S_ * XPH_ST);

    __syncthreads();

    for (int l = 0; l < L_; ++l) {
        const __half* linb = lin_all + (size_t)(l * B_ + b) * S_ * GG;

        // ---- phase 1: x = LN(lin + seq) -> fp16 k-pair transposed into xt2 ----
        #pragma unroll
        for (int p = 0; p < 2; ++p) {
            const int r = g8 + 64 * p;
            F4H8 lu; lu.f4 = *(const float4*)&linb[(size_t)r * GG + c8];
            float4 s0 = *(const float4*)&seqb[r * SEQ_ST + c8];
            float4 s1 = *(const float4*)&seqb[r * SEQ_ST + c8 + 4];
            float2 l0 = __half22float2(lu.hh[0]);
            float2 l1 = __half22float2(lu.hh[1]);
            float2 l2 = __half22float2(lu.hh[2]);
            float2 l3 = __half22float2(lu.hh[3]);
            float v[8];
            v[0] = l0.x + s0.x; v[1] = l0.y + s0.y; v[2] = l1.x + s0.z; v[3] = l1.y + s0.w;
            v[4] = l2.x + s1.x; v[5] = l2.y + s1.y; v[6] = l3.x + s1.z; v[7] = l3.y + s1.w;
            float s = 0.f;
            #pragma unroll
            for (int j = 0; j < 8; ++j) s += v[j];
            #pragma unroll
            for (int off = 1; off < 8; off <<= 1) s += __shfl_xor(s, off);
            const float mean = s * 0.015625f;
            float q = 0.f;
            float d[8];
            #pragma unroll
            for (int j = 0; j < 8; ++j) { d[j] = v[j] - mean; q += d[j] * d[j]; }
            #pragma unroll
            for (int off = 1; off < 8; off <<= 1) q += __shfl_xor(q, off);
            const float rstd = rsqrtf(q * 0.015625f + LN_EPS);
            float4 g0 = *(const float4*)&ln_g[c8];
            float4 g1 = *(const float4*)&ln_g[c8 + 4];
            float4 b0 = *(const float4*)&ln_b[c8];
            float4 b1 = *(const float4*)&ln_b[c8 + 4];
            float x[8];
            x[0] = d[0] * rstd * g0.x + b0.x; x[1] = d[1] * rstd * g0.y + b0.y;
            x[2] = d[2] * rstd * g0.z + b0.z; x[3] = d[3] * rstd * g0.w + b0.w;
            x[4] = d[4] * rstd * g1.x + b1.x; x[5] = d[5] * rstd * g1.y + b1.y;
            x[6] = d[6] * rstd * g1.z + b1.z; x[7] = d[7] * rstd * g1.w + b1.w;
            #pragma unroll
            for (int j = 0; j < 4; ++j)
                xt2[(c8 / 2 + j) * XT_ST + r] = __floats2half2_rn(x[2 * j], x[2 * j + 1]);
        }
        __syncthreads();

        // ---- phase 2: xp = x @ Wk + bias0 via v_dot2_f32_f16 (all LDS-resident) ----
        {
            float acc[4][12];
            #pragma unroll
            for (int m = 0; m < 12; ++m) {
                const float bi = bias0[cc + m];
                acc[0][m] = bi; acc[1][m] = bi; acc[2][m] = bi; acc[3][m] = bi;
            }
            #pragma unroll 4
            for (int k2 = 0; k2 < 32; ++k2) {
                FH2 x0, x1, x2, x3;
                x0.hh = xt2[k2 * XT_ST + rgrp];
                x1.hh = xt2[k2 * XT_ST + rgrp + 32];
                x2.hh = xt2[k2 * XT_ST + rgrp + 64];
                x3.hh = xt2[k2 * XT_ST + rgrp + 96];
                F4H8 wa, wb, wc;
                wa.f4 = *(const float4*)&wkd[k2 * WK_ST + cc];
                wb.f4 = *(const float4*)&wkd[k2 * WK_ST + cc + 4];
                wc.f4 = *(const float4*)&wkd[k2 * WK_ST + cc + 8];
                #pragma unroll
                for (int m = 0; m < 4; ++m) {
                    acc[0][m]     = __builtin_amdgcn_fdot2(x0.h, wa.h[m], acc[0][m],     false);
                    acc[1][m]     = __builtin_amdgcn_fdot2(x1.h, wa.h[m], acc[1][m],     false);
                    acc[2][m]     = __builtin_amdgcn_fdot2(x2.h, wa.h[m], acc[2][m],     false);
                    acc[3][m]     = __builtin_amdgcn_fdot2(x3.h, wa.h[m], acc[3][m],     false);
                    acc[0][m + 4] = __builtin_amdgcn_fdot2(x0.h, wb.h[m], acc[0][m + 4], false);
                    acc[1][m + 4] = __builtin_amdgcn_fdot2(x1.h, wb.h[m], acc[1][m + 4], false);
                    acc[2][m + 4] = __builtin_amdgcn_fdot2(x2.h, wb.h[m], acc[2][m + 4], false);
                    acc[3][m + 4] = __builtin_amdgcn_fdot2(x3.h, wb.h[m], acc[3][m + 4], false);
                    acc[0][m + 8] = __builtin_amdgcn_fdot2(x0.h, wc.h[m], acc[0][m + 8], false);
                    acc[1][m + 8] = __builtin_amdgcn_fdot2(x1.h, wc.h[m], acc[1][m + 8], false);
                    acc[2][m + 8] = __builtin_amdgcn_fdot2(x2.h, wc.h[m], acc[2][m + 8], false);
                    acc[3][m + 8] = __builtin_amdgcn_fdot2(x3.h, wc.h[m], acc[3][m + 8], false);
                }
            }
            #pragma unroll
            for (int i = 0; i < 4; ++i) {
                const int r = rgrp + 32 * i;
                __half2* dst = (__half2*)&xpd[r * XPH_ST + cc];
                #pragma unroll
                for (int j = 0; j < 6; ++j)
                    dst[j] = __floats2half2_rn(acc[i][2 * j], acc[i][2 * j + 1]);
            }
        }
        __syncthreads();

        // ---- phase 3: half-dot scan; row-local DPP butterfly + permlane combines (no LDS on h-chain) ----
        if (wave < 2) {
            const int dir = wave;
            const __half* xp = xph + dir * (S_ * XPH_ST);
            float* sq = seqb + dir * NU + (lane & 31);
            const int stp = dir ? -1 : 1;
            int s = dir ? (S_ - 1) : 0;
            const bool wl = (lane < 32);
            const bool fix = (b4 != b5);
            float xz = (float)xp[s * XPH_ST + ud];
            float xr = (float)xp[s * XPH_ST + 32 + ud];
            float xh = (float)xp[s * XPH_ST + 64 + ud];
            for (int st = 0; st < S_; ++st) {
                float nz = 0.f, nr = 0.f, nh = 0.f;
                if (st < S_ - 1) {
                    const int sn = s + stp;
                    nz = (float)xp[sn * XPH_ST + ud];
                    nr = (float)xp[sn * XPH_ST + 32 + ud];
                    nh = (float)xp[sn * XPH_ST + 64 + ud];
                }
                // row-local butterfly: ro[m] = (h[BB + v16^ex[m]], h[BB + v16^ey[m]])
                v2f ro[8];
                ro[0].x = h_store;                ro[0].y = dppf<DPP_X1>(h_store);
                ro[1].x = dppf<DPP_X2>(ro[0].x);  ro[1].y = dppf<DPP_X2>(ro[0].y);
                ro[2].x = dppf<DPP_X7>(ro[0].x);  ro[2].y = dppf<DPP_X7>(ro[0].y);
                ro[3].x = dppf<DPP_X7>(ro[1].x);  ro[3].y = dppf<DPP_X7>(ro[1].y);
                ro[4].x = dppf<DPP_X15>(ro[0].x); ro[4].y = dppf<DPP_X15>(ro[0].y);
                ro[5].x = dppf<DPP_X15>(ro[1].x); ro[5].y = dppf<DPP_X15>(ro[1].y);
                ro[6].x = dppf<DPP_X15>(ro[2].x); ro[6].y = dppf<DPP_X15>(ro[2].y);
                ro[7].x = dppf<DPP_X15>(ro[3].x); ro[7].y = dppf<DPP_X15>(ro[3].y);

                // half-dots (16 terms); bias/x pre-halved (partner adds it too)
                v2f az = v2f{0.5f * xz + rbz2, 0.f};
                v2f ar = v2f{0.5f * xr + rbr2, 0.f};
                v2f ah = v2f{rbh2, 0.f};
                #pragma unroll
                for (int m = 0; m < 8; ++m) {
                    pkfma(az, ro[m], wz[m]);
                    pkfma(ar, ro[m], wr_[m]);
                    pkfma(ah, ro[m], wh[m]);
                }
                const float pz = pairsum16(az.x + az.y);
                const float pr = pairsum16(ar.x + ar.y);
                const float ph = pairsum16(ah.x + ah.y);

                const float z  = sigmoidf_(pz);
                const float r  = sigmoidf_(pr);
                const float hh = tanhf_(xh + r * ph);
                const float hn_raw = hh + z * (h_dot - hh);
                h_dot = hn_raw;
                // placement: rows with b4!=b5 take the l^32 duplicate (verified permlane32)
                uv2 s32 = __builtin_amdgcn_permlane32_swap(
                    __float_as_uint(hn_raw), __float_as_uint(hn_raw), false, false);
                const float v32 = wl ? __uint_as_float(s32.y) : __uint_as_float(s32.x);
                h_store = fix ? v32 : hn_raw;
                if (wl) sq[s * SEQ_ST] = h_store;     // lanes<32: u_store = lane&31
                s += stp; xz = nz; xr = nr; xh = nh;
            }
        }
        __syncthreads();
    }

    // ---- final h + classifier ----
    if (wave < 2 && lane < 32) (wave ? hbb : hbf)[lane & 31] = h_store;
    __syncthreads();
    if (t == 0) {
        float l0 = b_cls[0], l1 = b_cls[1];
        for (int j = 0; j < NU; ++j) {
            const float hf = hbf[j], hk = hbb[j];
            l0 += hf * W_cls[4 * j]     + hk * W_cls[4 * j + 2];
            l1 += hf * W_cls[4 * j + 1] + hk * W_cls[4 * j + 3];
        }
        const float m = fmaxf(l0, l1);
        const float e0 = __expf(l0 - m), e1 = __expf(l1 - m);
        const float inv = 1.0f / (e0 + e1);
        out[b * 2 + 0] = e0 * inv;
        out[b * 2 + 1] = e1 * inv;
    }
}

extern "C" void kernel_launch(void* const* d_in, const int* in_sizes, int n_in,
                              void* d_out, int out_size, void* d_ws, size_t ws_size,
                              hipStream_t stream) {
    const float* xs    = (const float*)d_in[0];
    const float* W_lin = (const float*)d_in[1];
    const float* b_lin = (const float*)d_in[2];
    const float* ln_g  = (const float*)d_in[3];
    const float* ln_b  = (const float*)d_in[4];
    const float* Wk_f  = (const float*)d_in[5];
    const float* Wr_f  = (const float*)d_in[6];
    const float* b_f   = (const float*)d_in[7];
    const float* Wk_b  = (const float*)d_in[8];
    const float* Wr_b  = (const float*)d_in[9];
    const float* b_b   = (const float*)d_in[10];
    const float* W_cls = (const float*)d_in[11];
    const float* b_cls = (const float*)d_in[12];
    float* out = (float*)d_out;

    __half* lin_all = (__half*)d_ws;   // 13*4096*64 fp16 = 6,815,744 B

    // floats: seqb 8704 + xt2 4128 + wk2 6400 + xph 12800 + hb 64 = 32,096 -> 128,384 B
    const int smem = (8704 + 4128 + 6400 + 12800 + 64) * (int)sizeof(float);
    (void)hipFuncSetAttribute((const void*)chain_kernel,
                              hipFuncAttributeMaxDynamicSharedMemorySize, smem);

    lin_kernel<<<(L_ * B_ * S_) / 64, 256, 0, stream>>>(xs, W_lin, b_lin, lin_all);

    chain_kernel<<<B_, 512, smem, stream>>>(
        lin_all, Wr_f, b_f, Wr_b, b_b, Wk_f, Wk_b, ln_g, ln_b, W_cls, b_cls, out);
}